// Round 6
// baseline (297.695 us; speedup 1.0000x reference)
//
#include <hip/hip_runtime.h>

typedef float v2f __attribute__((ext_vector_type(2)));

#define TX 64
#define TY 20
#define PROWS (TY + 10)            // 30 rows of h-blurred data per tile
#define HSTR 67                    // scalar stride: 67%32=3 -> 2-way max (free)
#define IMW 512
#define IMH 512
#define NPLANES 96                 // 32 * 3
#define NBX (IMW / TX)             // 8
#define NBY ((IMH + TY - 1) / TY)  // 26
#define NBLOCKS (NBX * NBY * NPLANES)  // 19968

// Gaussian(sigma=1.5, ws=11), double-computed, fp32-rounded (passed at absmax 0).
#define GW0 0.00102838f
#define GW1 0.00759877f
#define GW2 0.03600077f
#define GW3 0.10936069f
#define GW4 0.21300553f
#define GW5 0.26601172f

__device__ __forceinline__ void pkfma(v2f& acc, v2f a, v2f b) {
  asm("v_pk_fma_f32 %0, %1, %2, %0" : "+v"(acc) : "v"(a), "v"(b));
}
__device__ __forceinline__ v2f pkmul(v2f a, v2f b) {
  v2f d;
  asm("v_pk_mul_f32 %0, %1, %2" : "=v"(d) : "v"(a), "v"(b));
  return d;
}

__global__ __launch_bounds__(256, 4) void ssim_main(
    const float* __restrict__ gen, const float* __restrict__ ref,
    float* __restrict__ partial) {
  // 5 scalar arrays, stride 67: phase-1 writes and phase-2 reads both <=2-way
  // (free per m136). 40,200 B -> 4 blocks/CU (proven in r2/r5).
  __shared__ float s_q[5][PROWS][HSTR];
  __shared__ float swsum[4];

  const float GW[11] = {GW0, GW1, GW2, GW3, GW4, GW5,
                        GW4, GW3, GW2, GW1, GW0};

  const int tid = threadIdx.x;
  const int bid = blockIdx.x;
  const int rem = bid % (NBX * NBY);
  const int plane = bid / (NBX * NBY);
  const int bx = rem % NBX;
  const int by = rem / NBX;
  const int x0 = bx * TX;
  const int y0 = by * TY;
  const float* gp = gen + (size_t)plane * (IMW * IMH);
  const float* rp = ref + (size_t)plane * (IMW * IMH);

  // ---- Phase 1: horizontal 11-tap blur, direct-from-global, packed regs.
  // 240 threads: (row 0..29) x (8 runs of 8 outputs). Window = 24 floats
  // loaded as 6 aligned float4 (each fully in or fully out of the image).
  if (tid < PROWS * 8) {
    const int row = tid >> 3;
    const int xs = (tid & 7) * 8;
    const int gy = y0 - 5 + row;
    const int xbase = x0 + xs - 8;  // window cols [xbase, xbase+24)
    const float* grow = gp + (size_t)gy * IMW;
    const float* rrow = rp + (size_t)gy * IMW;

    v2f P[24];  // (g, r) transformed, packed per column
    const bool interior = (bx >= 1) & (bx <= 6) & (by >= 1) & (by <= 24);
    if (interior) {
#pragma unroll
      for (int k = 0; k < 6; ++k) {
        const int c = xbase + 4 * k;
        const float4 g4 = *(const float4*)(grow + c);
        const float4 r4 = *(const float4*)(rrow + c);
        P[4 * k + 0] = (v2f){fmaf(0.5f, g4.x, 0.5f), fmaf(0.5f, r4.x, 0.5f)};
        P[4 * k + 1] = (v2f){fmaf(0.5f, g4.y, 0.5f), fmaf(0.5f, r4.y, 0.5f)};
        P[4 * k + 2] = (v2f){fmaf(0.5f, g4.z, 0.5f), fmaf(0.5f, r4.z, 0.5f)};
        P[4 * k + 3] = (v2f){fmaf(0.5f, g4.w, 0.5f), fmaf(0.5f, r4.w, 0.5f)};
      }
    } else {
      const bool rowok = (gy >= 0) && (gy < IMH);
#pragma unroll
      for (int k = 0; k < 6; ++k) {
        const int c = xbase + 4 * k;
        const bool ok = rowok && (c >= 0) && (c < IMW);
        float4 g4 = make_float4(-1.f, -1.f, -1.f, -1.f);
        float4 r4 = g4;  // transform maps -1 -> 0 (matches zero padding)
        if (ok) {
          g4 = *(const float4*)(grow + c);
          r4 = *(const float4*)(rrow + c);
        }
        P[4 * k + 0] = (v2f){fmaf(0.5f, g4.x, 0.5f), fmaf(0.5f, r4.x, 0.5f)};
        P[4 * k + 1] = (v2f){fmaf(0.5f, g4.y, 0.5f), fmaf(0.5f, r4.y, 0.5f)};
        P[4 * k + 2] = (v2f){fmaf(0.5f, g4.z, 0.5f), fmaf(0.5f, r4.z, 0.5f)};
        P[4 * k + 3] = (v2f){fmaf(0.5f, g4.w, 0.5f), fmaf(0.5f, r4.w, 0.5f)};
      }
    }

    v2f accP[8], accQ[8];
    float accS[8];
#pragma unroll
    for (int o = 0; o < 8; ++o) {
      accP[o] = (v2f){0.f, 0.f};
      accQ[o] = (v2f){0.f, 0.f};
      accS[o] = 0.f;
    }

#pragma unroll
    for (int p = 0; p < 18; ++p) {   // window position; col value = P[p+3]
      const v2f pv = P[p + 3];
      const v2f qv = pkmul(pv, pv);
      const float sv = pv.x * pv.y;
      const int olo = (p - 10 < 0) ? 0 : p - 10;
      const int ohi = (p < 7) ? p : 7;
#pragma unroll
      for (int o = olo; o <= ohi; ++o) {
        const float wt = GW[p - o];
        const v2f wv = (v2f){wt, wt};
        pkfma(accP[o], wv, pv);
        pkfma(accQ[o], wv, qv);
        accS[o] = fmaf(wt, sv, accS[o]);
      }
    }

    // Component-wise scalar stores; compiler pairs them into ds_write2_b32.
#pragma unroll
    for (int o = 0; o < 8; ++o) s_q[0][row][xs + o] = accP[o].x;
#pragma unroll
    for (int o = 0; o < 8; ++o) s_q[1][row][xs + o] = accP[o].y;
#pragma unroll
    for (int o = 0; o < 8; ++o) s_q[2][row][xs + o] = accQ[o].x;
#pragma unroll
    for (int o = 0; o < 8; ++o) s_q[3][row][xs + o] = accQ[o].y;
#pragma unroll
    for (int o = 0; o < 8; ++o) s_q[4][row][xs + o] = accS[o];
  }
  __syncthreads();

  // ---- Phase 2: vertical 11-tap blur + SSIM. 64 cols x 4 groups x 5 rows.
  // ROW-OUTER / OUTPUT-INNER: each accumulator touched once per ~15 instrs
  // (was every ~3 -> pk_fma latency chain). LDS values loaded once, consumed
  // immediately (low live-register count).
  const int col = tid & 63;
  const int r0 = (tid >> 6) * 5;

  v2f mu[5], ee[5];
  float e12[5];
#pragma unroll
  for (int o = 0; o < 5; ++o) {
    mu[o] = (v2f){0.f, 0.f};
    ee[o] = (v2f){0.f, 0.f};
    e12[o] = 0.f;
  }

#pragma unroll
  for (int i = 0; i < 15; ++i) {
    const v2f hp = (v2f){s_q[0][r0 + i][col], s_q[1][r0 + i][col]};
    const v2f hq = (v2f){s_q[2][r0 + i][col], s_q[3][r0 + i][col]};
    const float hs = s_q[4][r0 + i][col];
    const int olo = (i - 10 < 0) ? 0 : i - 10;
    const int ohi = (i < 4) ? i : 4;
#pragma unroll
    for (int o = olo; o <= ohi; ++o) {
      const float wt = GW[i - o];
      const v2f wv = (v2f){wt, wt};
      pkfma(mu[o], wv, hp);
      pkfma(ee[o], wv, hq);
      e12[o] = fmaf(wt, hs, e12[o]);
    }
  }

  const float C1 = 6.5025f, C2 = 58.5225f;
  float lsum = 0.f;
#pragma unroll
  for (int o = 0; o < 5; ++o) {
    const float mu1 = mu[o].x, mu2 = mu[o].y, e1 = ee[o].x, e2 = ee[o].y;
    const float m12 = mu1 * mu2;
    const float m1s = mu1 * mu1;
    const float m2s = mu2 * mu2;
    const float num = (2.f * m12 + C1) * (2.f * (e12[o] - m12) + C2);
    const float den = (m1s + m2s + C1) * ((e1 - m1s) + (e2 - m2s) + C2);
    const int y = y0 + r0 + o;
    lsum += (y < IMH) ? __fdividef(num, den) : 0.f;
  }

  // Block reduction -> deterministic per-block partial.
#pragma unroll
  for (int off = 32; off > 0; off >>= 1) lsum += __shfl_down(lsum, off, 64);
  if ((tid & 63) == 0) swsum[tid >> 6] = lsum;
  __syncthreads();
  if (tid == 0) partial[bid] = swsum[0] + swsum[1] + swsum[2] + swsum[3];
}

__global__ void ssim_reduce(const float* __restrict__ partial,
                            float* __restrict__ out) {
  const int nv = NBLOCKS / 4;  // 4992 float4
  double s = 0.0;
  for (int i = threadIdx.x; i < nv; i += 256) {
    float4 v = ((const float4*)partial)[i];
    s += (double)v.x + (double)v.y + (double)v.z + (double)v.w;
  }
#pragma unroll
  for (int off = 32; off > 0; off >>= 1) s += __shfl_down(s, off, 64);
  __shared__ double sd[4];
  if ((threadIdx.x & 63) == 0) sd[threadIdx.x >> 6] = s;
  __syncthreads();
  if (threadIdx.x == 0) {
    double npix = (double)NPLANES * (double)IMW * (double)IMH;
    out[0] = (float)(1.0 - (sd[0] + sd[1] + sd[2] + sd[3]) / npix);
  }
}

extern "C" void kernel_launch(void* const* d_in, const int* in_sizes, int n_in,
                              void* d_out, int out_size, void* d_ws, size_t ws_size,
                              hipStream_t stream) {
  (void)in_sizes; (void)n_in; (void)out_size; (void)ws_size;
  const float* gen = (const float*)d_in[0];
  const float* ref = (const float*)d_in[1];
  float* partial = (float*)d_ws;  // NBLOCKS floats; every slot written each call
  ssim_main<<<NBLOCKS, 256, 0, stream>>>(gen, ref, partial);
  ssim_reduce<<<1, 256, 0, stream>>>(partial, (float*)d_out);
}